// Round 1
// baseline (675.386 us; speedup 1.0000x reference)
//
#include <hip/hip_runtime.h>
#include <math.h>

#define SMOOTHING 0.1f
#define EPSILON_F 1e-8f

// Combine two online-softmax states (m,s) <- (m,s) ⊕ (mo,so)
__device__ __forceinline__ void osm_combine(float& m, float& s, float mo, float so) {
    float nm = fmaxf(m, mo);
    s = s * __expf(m - nm) + so * __expf(mo - nm);
    m = nm;
}

// One row (C=32000 fp32 logits) per 256-thread block.
// Computes masked label-smoothed loss for the row into row_loss[row].
__global__ __launch_bounds__(256) void Seq2SeqLoss_row_kernel(
    const float* __restrict__ logits,
    const int*   __restrict__ gold,
    const int*   __restrict__ mask,
    const float* __restrict__ weight,
    float*       __restrict__ row_loss,
    int C)
{
    const int row = blockIdx.x;
    const int tid = threadIdx.x;
    const float* __restrict__ x = logits + (size_t)row * (size_t)C;

    const int C4 = C >> 2;                       // 8000 float4 per row
    const float4* __restrict__ x4 = (const float4*)x;
    const float4* __restrict__ w4 = (const float4*)weight;

    // 4 independent online-softmax chains (one per float4 slot) for ILP.
    float m0 = -1e30f, m1 = -1e30f, m2 = -1e30f, m3 = -1e30f;
    float s0 = 0.f, s1 = 0.f, s2 = 0.f, s3 = 0.f;
    float wd = 0.f, wsum = 0.f;

    for (int i = tid; i < C4; i += 256) {
        float4 v = x4[i];
        float4 w = w4[i];

        // online softmax update, single exp per element:
        // nm = max(m,x); one of exp(m-nm), exp(x-nm) is exp(0)=1.
        {
            float d = v.x - m0; float e = __expf(-fabsf(d)); bool gt = d > 0.f;
            s0 = fmaf(s0, gt ? e : 1.0f, gt ? 1.0f : e); m0 = fmaxf(m0, v.x);
        }
        {
            float d = v.y - m1; float e = __expf(-fabsf(d)); bool gt = d > 0.f;
            s1 = fmaf(s1, gt ? e : 1.0f, gt ? 1.0f : e); m1 = fmaxf(m1, v.y);
        }
        {
            float d = v.z - m2; float e = __expf(-fabsf(d)); bool gt = d > 0.f;
            s2 = fmaf(s2, gt ? e : 1.0f, gt ? 1.0f : e); m2 = fmaxf(m2, v.z);
        }
        {
            float d = v.w - m3; float e = __expf(-fabsf(d)); bool gt = d > 0.f;
            s3 = fmaf(s3, gt ? e : 1.0f, gt ? 1.0f : e); m3 = fmaxf(m3, v.w);
        }

        wd = fmaf(w.x, v.x, wd); wd = fmaf(w.y, v.y, wd);
        wd = fmaf(w.z, v.z, wd); wd = fmaf(w.w, v.w, wd);
        wsum += (w.x + w.y) + (w.z + w.w);
    }

    // merge the 4 per-thread chains
    osm_combine(m0, s0, m1, s1);
    osm_combine(m2, s2, m3, s3);
    osm_combine(m0, s0, m2, s2);
    float M = m0, S = s0;

    // wave(64)-level butterfly-ish reduce via shfl_down
    #pragma unroll
    for (int off = 32; off >= 1; off >>= 1) {
        float Mo = __shfl_down(M, off);
        float So = __shfl_down(S, off);
        wd   += __shfl_down(wd, off);
        wsum += __shfl_down(wsum, off);
        osm_combine(M, S, Mo, So);
    }

    // cross-wave (4 waves) via LDS
    __shared__ float shM[4], shS[4], shWD[4], shWS[4];
    const int wave = tid >> 6;
    if ((tid & 63) == 0) { shM[wave] = M; shS[wave] = S; shWD[wave] = wd; shWS[wave] = wsum; }
    __syncthreads();

    if (tid == 0) {
        #pragma unroll
        for (int w = 1; w < 4; ++w) {
            osm_combine(M, S, shM[w], shS[w]);
            wd   += shWD[w];
            wsum += shWS[w];
        }
        float logZ = M + logf(S);

        int   g  = gold[row];
        float xg = x[g];
        float wg = weight[g];

        const float uniform    = SMOOTHING / (float)(C - 1);
        const float confidence = 1.0f - SMOOTHING;

        float total    = logZ * wsum - wd;        // sum_c w_c * (logZ - x_c)
        float gold_nll = logZ - xg;
        float loss = uniform * total + (confidence - uniform) * wg * gold_nll;

        loss *= (mask[row] != 0) ? 1.0f : 0.0f;
        row_loss[row] = loss;
    }
}

// Single-block deterministic finalize: out = sum(row_loss) / (sum(mask) + eps)
__global__ __launch_bounds__(256) void Seq2SeqLoss_finalize_kernel(
    const float* __restrict__ row_loss,
    const int*   __restrict__ mask,
    float*       __restrict__ out,
    int N)
{
    const int tid = threadIdx.x;
    float acc = 0.f, cnt = 0.f;
    for (int i = tid; i < N; i += 256) {
        acc += row_loss[i];
        cnt += (mask[i] != 0) ? 1.0f : 0.0f;
    }
    #pragma unroll
    for (int off = 32; off >= 1; off >>= 1) {
        acc += __shfl_down(acc, off);
        cnt += __shfl_down(cnt, off);
    }
    __shared__ float shA[4], shC[4];
    const int wave = tid >> 6;
    if ((tid & 63) == 0) { shA[wave] = acc; shC[wave] = cnt; }
    __syncthreads();
    if (tid == 0) {
        #pragma unroll
        for (int w = 1; w < 4; ++w) { acc += shA[w]; cnt += shC[w]; }
        out[0] = acc / (cnt + EPSILON_F);
    }
}

extern "C" void kernel_launch(void* const* d_in, const int* in_sizes, int n_in,
                              void* d_out, int out_size, void* d_ws, size_t ws_size,
                              hipStream_t stream) {
    const float* logits = (const float*)d_in[0];   // [B,S,C] fp32
    const int*   gold   = (const int*)d_in[1];     // [B,S]   (int64 in ref -> int32 here)
    const int*   mask   = (const int*)d_in[2];     // [B,S]   (bool in ref -> int32 here)
    const float* weight = (const float*)d_in[3];   // [C]     fp32

    const int N = in_sizes[1];   // B*S = 4096 rows
    const int C = in_sizes[3];   // 32000 classes

    float* row_loss = (float*)d_ws;  // N floats = 16 KB scratch

    Seq2SeqLoss_row_kernel<<<N, 256, 0, stream>>>(logits, gold, mask, weight, row_loss, C);
    Seq2SeqLoss_finalize_kernel<<<1, 256, 0, stream>>>(row_loss, mask, (float*)d_out, N);
}

// Round 2
// 671.747 us; speedup vs baseline: 1.0054x; 1.0054x over previous
//
#include <hip/hip_runtime.h>
#include <math.h>

#define SMOOTHING 0.1f
#define EPSILON_F 1e-8f

// Combine two online-softmax states (m,s) <- (m,s) ⊕ (mo,so)
__device__ __forceinline__ void osm_combine(float& m, float& s, float mo, float so) {
    float nm = fmaxf(m, mo);
    s = s * __expf(m - nm) + so * __expf(mo - nm);
    m = nm;
}

// Chunked online-softmax update over one float4 + weighted-dot accumulation.
// Loop-carried chain: fmax -> sub -> exp -> fma (per 4 elements, not per element).
__device__ __forceinline__ void osm_update4(float& m, float& s, float4 v,
                                            float4 w, float& wd, float& ws) {
    float c01 = fmaxf(v.x, v.y);
    float c23 = fmaxf(v.z, v.w);
    float cm  = fmaxf(c01, c23);
    float nm  = fmaxf(m, cm);
    float e   = __expf(m - nm);
    float e0  = __expf(v.x - nm);
    float e1  = __expf(v.y - nm);
    float e2  = __expf(v.z - nm);
    float e3  = __expf(v.w - nm);
    s = fmaf(s, e, (e0 + e1) + (e2 + e3));
    m = nm;
    wd = fmaf(w.x, v.x, wd);
    wd = fmaf(w.y, v.y, wd);
    wd = fmaf(w.z, v.z, wd);
    wd = fmaf(w.w, v.w, wd);
    ws += (w.x + w.y) + (w.z + w.w);
}

// One row (C fp32 logits) per 256-thread block. Two independent online-softmax
// chains (front/back half of the row) for ILP; both float4 loads issued
// back-to-back each iteration to keep bytes in flight.
__global__ __launch_bounds__(256) void Seq2SeqLoss_row_kernel(
    const float* __restrict__ logits,
    const int*   __restrict__ gold,
    const int*   __restrict__ mask,
    const float* __restrict__ weight,
    float*       __restrict__ row_loss,
    int C)
{
    const int row = blockIdx.x;
    const int tid = threadIdx.x;
    const float* __restrict__ x = logits + (size_t)row * (size_t)C;

    const int C4   = C >> 2;        // float4 count (C % 4 == 0)
    const int half = C4 >> 1;       // two chains: [0,half) and [half,2*half)
    const float4* __restrict__ x4 = (const float4*)x;
    const float4* __restrict__ w4 = (const float4*)weight;

    float m0 = -1e30f, s0 = 0.f;
    float m1 = -1e30f, s1 = 0.f;
    float wd = 0.f, wsum = 0.f;

    for (int i = tid; i < half; i += 256) {
        float4 a  = x4[i];
        float4 b  = x4[i + half];
        float4 wa = w4[i];
        float4 wb = w4[i + half];
        osm_update4(m0, s0, a, wa, wd, wsum);
        osm_update4(m1, s1, b, wb, wd, wsum);
    }
    // tail if C4 is odd (not hit for C=32000)
    for (int i = (half << 1) + tid; i < C4; i += 256) {
        float4 a  = x4[i];
        float4 wa = w4[i];
        osm_update4(m0, s0, a, wa, wd, wsum);
    }

    osm_combine(m0, s0, m1, s1);
    float M = m0, S = s0;

    // wave(64)-level reduce
    #pragma unroll
    for (int off = 32; off >= 1; off >>= 1) {
        float Mo = __shfl_down(M, off);
        float So = __shfl_down(S, off);
        wd   += __shfl_down(wd, off);
        wsum += __shfl_down(wsum, off);
        osm_combine(M, S, Mo, So);
    }

    // cross-wave (4 waves) via LDS
    __shared__ float shM[4], shS[4], shWD[4], shWS[4];
    const int wave = tid >> 6;
    if ((tid & 63) == 0) { shM[wave] = M; shS[wave] = S; shWD[wave] = wd; shWS[wave] = wsum; }
    __syncthreads();

    if (tid == 0) {
        #pragma unroll
        for (int w = 1; w < 4; ++w) {
            osm_combine(M, S, shM[w], shS[w]);
            wd   += shWD[w];
            wsum += shWS[w];
        }
        float logZ = M + logf(S);

        int   g  = gold[row];
        float xg = x[g];
        float wg = weight[g];

        const float uniform    = SMOOTHING / (float)(C - 1);
        const float confidence = 1.0f - SMOOTHING;

        float total    = logZ * wsum - wd;        // sum_c w_c * (logZ - x_c)
        float gold_nll = logZ - xg;
        float loss = uniform * total + (confidence - uniform) * wg * gold_nll;

        loss *= (mask[row] != 0) ? 1.0f : 0.0f;
        row_loss[row] = loss;
    }
}

// Single-block deterministic finalize: out = sum(row_loss) / (sum(mask) + eps)
__global__ __launch_bounds__(256) void Seq2SeqLoss_finalize_kernel(
    const float* __restrict__ row_loss,
    const int*   __restrict__ mask,
    float*       __restrict__ out,
    int N)
{
    const int tid = threadIdx.x;
    float acc = 0.f, cnt = 0.f;
    for (int i = tid; i < N; i += 256) {
        acc += row_loss[i];
        cnt += (mask[i] != 0) ? 1.0f : 0.0f;
    }
    #pragma unroll
    for (int off = 32; off >= 1; off >>= 1) {
        acc += __shfl_down(acc, off);
        cnt += __shfl_down(cnt, off);
    }
    __shared__ float shA[4], shC[4];
    const int wave = tid >> 6;
    if ((tid & 63) == 0) { shA[wave] = acc; shC[wave] = cnt; }
    __syncthreads();
    if (tid == 0) {
        #pragma unroll
        for (int w = 1; w < 4; ++w) { acc += shA[w]; cnt += shC[w]; }
        out[0] = acc / (cnt + EPSILON_F);
    }
}

extern "C" void kernel_launch(void* const* d_in, const int* in_sizes, int n_in,
                              void* d_out, int out_size, void* d_ws, size_t ws_size,
                              hipStream_t stream) {
    const float* logits = (const float*)d_in[0];   // [B,S,C] fp32
    const int*   gold   = (const int*)d_in[1];     // [B,S]   (int64 in ref -> int32 here)
    const int*   mask   = (const int*)d_in[2];     // [B,S]   (bool in ref -> int32 here)
    const float* weight = (const float*)d_in[3];   // [C]     fp32

    const int N = in_sizes[1];   // B*S = 4096 rows
    const int C = in_sizes[3];   // 32000 classes

    float* row_loss = (float*)d_ws;  // N floats = 16 KB scratch

    Seq2SeqLoss_row_kernel<<<N, 256, 0, stream>>>(logits, gold, mask, weight, row_loss, C);
    Seq2SeqLoss_finalize_kernel<<<1, 256, 0, stream>>>(row_loss, mask, (float*)d_out, N);
}